// Round 1
// baseline (227.817 us; speedup 1.0000x reference)
//
#include <hip/hip_runtime.h>

// Sparsemax over rows: B=131072, D=256, fp32.
// One 64-lane wave per row; each lane holds 4 contiguous elements (float4).
// tau found by Michelot's algorithm (exact simplex projection, same tau as
// the reference's sort-based formula): iterate tau = (sum_{z>tau} z - 1)/count
// until the active-set count stops changing. Converges in ~3-6 iters for
// Gaussian inputs; capped at 64 for safety (monotone shrinking set => finite).

#define D_COLS 256

__global__ __launch_bounds__(256) void sparsemax_kernel(
    const float* __restrict__ x, float* __restrict__ out, int nrows) {
  const int wave = threadIdx.x >> 6;
  const int lane = threadIdx.x & 63;
  const int row = blockIdx.x * 4 + wave;
  if (row >= nrows) return;

  const float4* rp = (const float4*)(x + (size_t)row * D_COLS);
  float4 v = rp[lane];

  // Total row sum -> initial tau with full support.
  float s = (v.x + v.y) + (v.z + v.w);
  #pragma unroll
  for (int off = 32; off > 0; off >>= 1) s += __shfl_xor(s, off, 64);

  float tau = (s - 1.0f) * (1.0f / 256.0f);
  float prev_c = 256.0f;

  // Michelot fixed-point iteration (wave-uniform control flow).
  for (int it = 0; it < 64; ++it) {
    unsigned long long m0 = __ballot(v.x > tau);
    unsigned long long m1 = __ballot(v.y > tau);
    unsigned long long m2 = __ballot(v.z > tau);
    unsigned long long m3 = __ballot(v.w > tau);
    float c = (float)(__popcll(m0) + __popcll(m1) + __popcll(m2) + __popcll(m3));

    float ls = ((v.x > tau) ? v.x : 0.0f) + ((v.y > tau) ? v.y : 0.0f) +
               ((v.z > tau) ? v.z : 0.0f) + ((v.w > tau) ? v.w : 0.0f);
    #pragma unroll
    for (int off = 32; off > 0; off >>= 1) ls += __shfl_xor(ls, off, 64);

    if (c == prev_c) break;          // set stable => tau is the answer
    tau = (ls - 1.0f) / c;
    prev_c = c;
  }

  float4 o;
  o.x = fmaxf(v.x - tau, 0.0f);
  o.y = fmaxf(v.y - tau, 0.0f);
  o.z = fmaxf(v.z - tau, 0.0f);
  o.w = fmaxf(v.w - tau, 0.0f);
  ((float4*)(out + (size_t)row * D_COLS))[lane] = o;
}

extern "C" void kernel_launch(void* const* d_in, const int* in_sizes, int n_in,
                              void* d_out, int out_size, void* d_ws, size_t ws_size,
                              hipStream_t stream) {
  const float* x = (const float*)d_in[0];
  float* out = (float*)d_out;
  const int nrows = in_sizes[0] / D_COLS;
  const int blocks = (nrows + 3) / 4;  // 4 rows (waves) per 256-thread block
  sparsemax_kernel<<<blocks, 256, 0, stream>>>(x, out, nrows);
}

// Round 2
// 217.061 us; speedup vs baseline: 1.0496x; 1.0496x over previous
//
#include <hip/hip_runtime.h>

// Sparsemax over rows: B=131072, D=256, fp32.
// One 64-lane wave per row; each lane holds 4 contiguous elements (float4).
// tau via Michelot's algorithm started from the tight superset A0={z>max-1}
// (valid since tau* ∈ [max-1, max)): ~2-3 iterations for Gaussian rows vs
// ~6-8 from the full set. Convergence check (ballot count, scalar pipe) runs
// BEFORE the sum butterfly, so the final iteration costs no reduction.

#define D_COLS 256

__global__ __launch_bounds__(256) void sparsemax_kernel(
    const float* __restrict__ x, float* __restrict__ out, int nrows) {
  const int wave = threadIdx.x >> 6;
  const int lane = threadIdx.x & 63;
  const int row = blockIdx.x * 4 + wave;
  if (row >= nrows) return;

  const float4* rp = (const float4*)(x + (size_t)row * D_COLS);
  float4 v = rp[lane];

  // Row max -> initial tau = max - 1 (lower bound on tau*, superset start).
  float m = fmaxf(fmaxf(v.x, v.y), fmaxf(v.z, v.w));
  #pragma unroll
  for (int off = 32; off > 0; off >>= 1) m = fmaxf(m, __shfl_xor(m, off, 64));

  float tau = m - 1.0f;
  float prev_c = -1.0f;  // impossible count => no break on first iteration

  for (int it = 0; it < 64; ++it) {
    unsigned long long m0 = __ballot(v.x > tau);
    unsigned long long m1 = __ballot(v.y > tau);
    unsigned long long m2 = __ballot(v.z > tau);
    unsigned long long m3 = __ballot(v.w > tau);
    float c = (float)(__popcll(m0) + __popcll(m1) + __popcll(m2) + __popcll(m3));

    if (c == prev_c) break;  // active set stable => tau is the fixed point

    float ls = ((v.x > tau) ? v.x : 0.0f) + ((v.y > tau) ? v.y : 0.0f) +
               ((v.z > tau) ? v.z : 0.0f) + ((v.w > tau) ? v.w : 0.0f);
    #pragma unroll
    for (int off = 32; off > 0; off >>= 1) ls += __shfl_xor(ls, off, 64);

    tau = (ls - 1.0f) / c;
    prev_c = c;
  }

  float4 o;
  o.x = fmaxf(v.x - tau, 0.0f);
  o.y = fmaxf(v.y - tau, 0.0f);
  o.z = fmaxf(v.z - tau, 0.0f);
  o.w = fmaxf(v.w - tau, 0.0f);
  ((float4*)(out + (size_t)row * D_COLS))[lane] = o;
}

extern "C" void kernel_launch(void* const* d_in, const int* in_sizes, int n_in,
                              void* d_out, int out_size, void* d_ws, size_t ws_size,
                              hipStream_t stream) {
  const float* x = (const float*)d_in[0];
  float* out = (float*)d_out;
  const int nrows = in_sizes[0] / D_COLS;
  const int blocks = (nrows + 3) / 4;  // 4 rows (waves) per 256-thread block
  sparsemax_kernel<<<blocks, 256, 0, stream>>>(x, out, nrows);
}